// Round 10
// baseline (92.541 us; speedup 1.0000x reference)
//
#include <hip/hip_runtime.h>
#include <cstdint>
#include <cstddef>

typedef unsigned short u16;
typedef unsigned int u32;
typedef u16 u16x4 __attribute__((ext_vector_type(4)));
typedef u16 u16x8 __attribute__((ext_vector_type(8)));
typedef u32 u32x2 __attribute__((ext_vector_type(2)));
typedef u32 u32x4 __attribute__((ext_vector_type(4)));
typedef _Float16 f16x8 __attribute__((ext_vector_type(8)));
typedef float f32x4 __attribute__((ext_vector_type(4)));

#define B_   2
#define N_   2048
#define F_   512
#define D_   512
#define W_   128
#define E3   1536
#define MTOT 4096
#define QK_ELEMS (MTOT * D_) /* 2,097,152 */

/* ===== R19 =====
 * R18 won (-1.1, 91.90). This round: GEMM occupancy+balance.
 * Old grid: 384 blocks x 4 waves = 1.5 blocks/CU = 1.5 waves/SIMD and a
 * 2-round makespan (2*T vs ideal 1.5*T). T_block~6.5us x 2 + launch ~= the
 * measured 15.9 us.
 * New: TM x TE = 128 x 64, grid (32,24) = 768 blocks = EXACTLY 3/CU:
 *  - perfect last-round balance + 12 waves/CU (3 waves/SIMD, 2x TLP)
 *  - wave tile 64x32 (acc[4][2], 8 MFMA/K-step); staging 2 A-rows + 1 B-row
 *    per thread; LDS 24KB dbuf; read swizzle formula unchanged
 *  - X re-read 24x but XCD-local (same-x blocks 32 apart, 32%8==0) and
 *    4 X-tiles = 1MB < 4MB L2
 * attn untouched (R18-proven). */

__device__ __forceinline__ u16 f2h(float f) {
  return __builtin_bit_cast(u16, (_Float16)f); /* v_cvt_f16_f32, RNE */
}
__device__ __forceinline__ u32 pk2h(float a, float b) {
  return __builtin_bit_cast(u32, __builtin_amdgcn_cvt_pkrtz(a, b));
}
__device__ __forceinline__ f32x4 mfma_f16(u16x8 a, u16x8 b, f32x4 c) {
  return __builtin_amdgcn_mfma_f32_16x16x32_f16(
      __builtin_bit_cast(f16x8, a), __builtin_bit_cast(f16x8, b), c, 0, 0, 0);
}

/* ---------------- QKV GEMM, fp32->fp16 reg-staged, 128x64 tile (R19) ------- */
#define TM 128
#define TE 64
#define BK 32
#define NK (F_ / BK) /* 16 */

__global__ __launch_bounds__(256) void qkv_gemm(const float* __restrict__ X,
                                                const float* __restrict__ Wl,
                                                u16* __restrict__ Qf,
                                                u16* __restrict__ Kf,
                                                u16* __restrict__ Vt) {
  /* dbuf 2 x (A 4096 + B 2048) u16 = 24576 B; vbuf 4 x 4224 B = 16896 B */
  __shared__ __align__(16) u16 smem[12288];

  const int tid = threadIdx.x;
  const int m0 = blockIdx.x * TM;
  const int e0 = blockIdx.y * TE;
  const int lane = tid & 63;
  const int wave = tid >> 6;
  const int wm = (wave >> 1) * 64; /* wave M-offset: 2 halves */
  const int we = (wave & 1) * 32;  /* wave E-offset: 2 halves */
  const int qd = lane >> 4;
  const int l16 = lane & 15;

  const int r0 = wave * 32;
  const int sr = lane >> 2; /* 0..15 */
  const int sc = lane & 3;  /* src chunk */
  const int key = (sr >> 1) & 3;
  const int cl = sc ^ key; /* LDS chunk */
  const int laA = (r0 + sr) * 32 + cl * 8;        /* A rows r0+sr, r0+16+sr */
  const int laB = (wave * 16 + sr) * 32 + cl * 8; /* B row wave*16+sr */

  const float* ga = X + (size_t)(m0 + r0 + sr) * F_ + sc * 8;
  const float* gb = Wl + (size_t)(e0 + wave * 16 + sr) * F_ + sc * 8;

  f32x4 acc[4][2];
#pragma unroll
  for (int i = 0; i < 4; ++i)
#pragma unroll
    for (int j = 0; j < 2; ++j) acc[i][j] = (f32x4){0.f, 0.f, 0.f, 0.f};

  const int swz = (l16 >> 1) & 3;
  const int rdoff = (qd ^ swz) * 8; /* R6-proven read swizzle (row%16 = l16) */

  /* Prologue: stage k=0 into buf0. */
  {
    float4 a0 = *(const float4*)(ga);
    float4 a1 = *(const float4*)(ga + 4);
    float4 a2 = *(const float4*)(ga + 16 * F_);
    float4 a3 = *(const float4*)(ga + 16 * F_ + 4);
    float4 b0 = *(const float4*)(gb);
    float4 b1 = *(const float4*)(gb + 4);
    u16* sA = smem;
    u16* sB = smem + 4096;
    *(u32x4*)&sA[laA] = (u32x4){pk2h(a0.x, a0.y), pk2h(a0.z, a0.w),
                                pk2h(a1.x, a1.y), pk2h(a1.z, a1.w)};
    *(u32x4*)&sA[laA + 512] = (u32x4){pk2h(a2.x, a2.y), pk2h(a2.z, a2.w),
                                      pk2h(a3.x, a3.y), pk2h(a3.z, a3.w)};
    *(u32x4*)&sB[laB] = (u32x4){pk2h(b0.x, b0.y), pk2h(b0.z, b0.w),
                                pk2h(b1.x, b1.y), pk2h(b1.z, b1.w)};
  }

  for (int k = 0; k < NK; ++k) {
    u16* sAk = smem + (k & 1) * 6144;
    u16* sBk = sAk + 4096;
    __syncthreads();

    u16x8 fA[4], fB[2];
#pragma unroll
    for (int mi = 0; mi < 4; ++mi)
      fA[mi] = *(const u16x8*)&sAk[(wm + mi * 16 + l16) * 32 + rdoff];
#pragma unroll
    for (int ei = 0; ei < 2; ++ei)
      fB[ei] = *(const u16x8*)&sBk[(we + ei * 16 + l16) * 32 + rdoff];

    /* Issue next tile's loads NOW; consumed after the MFMAs below. */
    float4 a0, a1, a2, a3, b0, b1;
    if (k + 1 < NK) {
      const float* gan = ga + (k + 1) * BK;
      const float* gbn = gb + (k + 1) * BK;
      a0 = *(const float4*)(gan);
      a1 = *(const float4*)(gan + 4);
      a2 = *(const float4*)(gan + 16 * F_);
      a3 = *(const float4*)(gan + 16 * F_ + 4);
      b0 = *(const float4*)(gbn);
      b1 = *(const float4*)(gbn + 4);
    }

#pragma unroll
    for (int mi = 0; mi < 4; ++mi)
#pragma unroll
      for (int ei = 0; ei < 2; ++ei)
        acc[mi][ei] = mfma_f16(fA[mi], fB[ei], acc[mi][ei]);

    if (k + 1 < NK) {
      u16* nA = smem + ((k + 1) & 1) * 6144;
      u16* nB = nA + 4096;
      *(u32x4*)&nA[laA] = (u32x4){pk2h(a0.x, a0.y), pk2h(a0.z, a0.w),
                                  pk2h(a1.x, a1.y), pk2h(a1.z, a1.w)};
      *(u32x4*)&nA[laA + 512] = (u32x4){pk2h(a2.x, a2.y), pk2h(a2.z, a2.w),
                                        pk2h(a3.x, a3.y), pk2h(a3.z, a3.w)};
      *(u32x4*)&nB[laB] = (u32x4){pk2h(b0.x, b0.y), pk2h(b0.z, b0.w),
                                  pk2h(b1.x, b1.y), pk2h(b1.z, b1.w)};
    }
  }

  /* C/D layout: row = qd*4 + reg, col = lane&15 */
  const int third = e0 >> 9; /* 0=Q, 1=K, 2=V */
  if (third < 2) {
    u16* P = third ? Kf : Qf;
    const int ecol0 = (e0 & 511) + we;
    const int odd = l16 & 1;
#pragma unroll
    for (int mi = 0; mi < 4; ++mi)
#pragma unroll
      for (int ei = 0; ei < 2; ++ei) {
        float x0 = acc[mi][ei][0], x1 = acc[mi][ei][1];
        float x2 = acc[mi][ei][2], x3 = acc[mi][ei][3];
        float t0 = __shfl_xor(x0, 1), t1 = __shfl_xor(x1, 1);
        float t2 = __shfl_xor(x2, 1), t3 = __shfl_xor(x3, 1);
        u32 pa = odd ? pk2h(t2, x2) : pk2h(x0, t0);
        u32 pb = odd ? pk2h(t3, x3) : pk2h(x1, t1);
        int mrow = m0 + wm + mi * 16 + qd * 4 + odd * 2;
        int colp = ecol0 + ei * 16 + (l16 & ~1);
        *(u32*)(P + (size_t)mrow * D_ + colp) = pa;
        *(u32*)(P + (size_t)(mrow + 1) * D_ + colp) = pb;
      }
  } else {
    /* V: per-wave 32e x 64m LDS transpose (stride 66 u16), coalesced write. */
    __syncthreads();
    u16* vbuf = smem + wave * 2112; /* [32][66] u16 = 4224 B */
#pragma unroll
    for (int mi = 0; mi < 4; ++mi)
#pragma unroll
      for (int ei = 0; ei < 2; ++ei)
#pragma unroll
        for (int r2 = 0; r2 < 2; ++r2) {
          int e_in = ei * 16 + l16;           /* 0..31 */
          int m_in = mi * 16 + qd * 4 + r2 * 2; /* 0..63 */
          u32 p = pk2h(acc[mi][ei][r2 * 2], acc[mi][ei][r2 * 2 + 1]);
          *(u32*)&vbuf[e_in * 66 + m_in] = p;
        }
    __builtin_amdgcn_s_waitcnt(0); /* drain lgkm before wave-local readback */
    const int dbase = (e0 - 1024) + we;
    const int mb = (m0 & 2047) + wm;
    const int bb = m0 >> 11;
    u16* vt = Vt + (size_t)bb * (D_ * N_);
#pragma unroll
    for (int it = 0; it < 2; ++it) {
      int e_in = it * 16 + (lane >> 2); /* 0..31 */
      int mc = lane & 3;
      u32 q0[8];
#pragma unroll
      for (int c4 = 0; c4 < 8; ++c4)
        q0[c4] = *(const u32*)&vbuf[e_in * 66 + mc * 16 + c4 * 2];
      u16* gp = vt + (size_t)(dbase + e_in) * N_ + mb + mc * 16;
      *(u32x4*)gp = (u32x4){q0[0], q0[1], q0[2], q0[3]};
      *(u32x4*)(gp + 8) = (u32x4){q0[4], q0[5], q0[6], q0[7]};
    }
  }
}

/* ---------------- MFMA sliding-window attention (R18-proven, 16 waves) -----
 * 256 blocks x 1024 threads; XCD swizzle; split-K 4-way x col 4-way;
 * phase 2 one wave/row; phase 3 wave owns 32 d-cols. */
#define TQA 16
#define SA 200
#define SP 208
#define NWG_A (MTOT / TQA) /* 256 */
#define CPX (NWG_A / 8)    /* 32 blocks per XCD chunk */

__global__ __launch_bounds__(1024) void attn_kernel(const u16* __restrict__ Qf,
                                                    const u16* __restrict__ Kf,
                                                    const u16* __restrict__ Vt,
                                                    float* __restrict__ Out) {
  const int bid = ((int)blockIdx.x & 7) * CPX + ((int)blockIdx.x >> 3);
  const int m0 = bid * TQA;
  const int b = m0 >> 11;
  const int n0 = m0 & 2047;
  const int t = threadIdx.x;
  const int lane = t & 63;
  const int w = t >> 6; /* 0..15 */
  const int qd = lane >> 4;
  const int l16 = lane & 15;

  __shared__ __align__(16) float att[4][TQA][SA]; /* 51.2 KB */
  __shared__ __align__(16) u16 pS[TQA][SP];       /* 6.7 KB */

  const int jw = w & 3;
  const int kh = w >> 2; /* 0..3 */
  const int ntm = (jw < 3) ? 3 : 1; /* col-tiles 0..9 (160 cols) */

  /* Phase 1: logits = Q K^T; split-K 4-way x col-split 4-way. */
  f32x4 acc[3];
#pragma unroll
  for (int nt = 0; nt < 3; ++nt) acc[nt] = (f32x4){0.f, 0.f, 0.f, 0.f};

  const size_t qrow = (size_t)(m0 + l16) * D_ + qd * 8;
  for (int ks = kh * 4; ks < kh * 4 + 4; ++ks) {
    u16x8 qv = *(const u16x8*)(Qf + qrow + ks * 32);
#pragma unroll
    for (int nt = 0; nt < 3; ++nt) {
      if (nt < ntm) {
        int j = (jw * 3 + nt) * 16 + l16;
        int rl = n0 - 128 + j;
        int rg = b * N_ + (rl > 0 ? rl : 0);
        u16x8 kv = *(const u16x8*)(Kf + (size_t)rg * D_ + ks * 32 + qd * 8);
        acc[nt] = mfma_f16(qv, kv, acc[nt]);
      }
    }
  }
#pragma unroll
  for (int nt = 0; nt < 3; ++nt)
    if (nt < ntm) {
#pragma unroll
      for (int r = 0; r < 4; ++r)
        att[kh][qd * 4 + r][(jw * 3 + nt) * 16 + l16] = acc[nt][r];
    }
  __syncthreads();

  /* Phase 2: softmax; wave w owns query row i=w; 64 lanes, 3 cols each. */
  {
    const int i = w;
    const int c = lane;
    float ev[3];
    float mx = -1e30f;
#pragma unroll
    for (int s = 0; s < 3; ++s) {
      int j = c + s * 64;
      bool inw = (j >= i + 1) && (j <= i + 128);
      float v = -1e30f;
      if (inw)
        v = (n0 - 128 + j < 0)
                ? 0.f
                : att[0][i][j] + att[1][i][j] + att[2][i][j] + att[3][i][j];
      ev[s] = v;
      mx = fmaxf(mx, v);
    }
    mx = fmaxf(mx, __shfl_xor(mx, 1));
    mx = fmaxf(mx, __shfl_xor(mx, 2));
    mx = fmaxf(mx, __shfl_xor(mx, 4));
    mx = fmaxf(mx, __shfl_xor(mx, 8));
    mx = fmaxf(mx, __shfl_xor(mx, 16));
    mx = fmaxf(mx, __shfl_xor(mx, 32));
    float sum = 0.f;
#pragma unroll
    for (int s = 0; s < 3; ++s) {
      ev[s] = (ev[s] > -1e29f) ? __expf(ev[s] - mx) : 0.f;
      sum += ev[s];
    }
    sum += __shfl_xor(sum, 1);
    sum += __shfl_xor(sum, 2);
    sum += __shfl_xor(sum, 4);
    sum += __shfl_xor(sum, 8);
    sum += __shfl_xor(sum, 16);
    sum += __shfl_xor(sum, 32);
    const float inv = 1.f / sum;
#pragma unroll
    for (int s = 0; s < 3; ++s) {
      int j = c + s * 64;
      if (j < 160) {
        bool zv = (n0 - 128 + j) < 0;
        pS[i][j] = zv ? (u16)0 : f2h(ev[s] * inv);
      }
    }
  }
  __syncthreads();

  /* Phase 3: Out = P V; wave w owns d-cols [w*32, w*32+32). kk<5. */
  f32x4 oacc[2];
#pragma unroll
  for (int nt = 0; nt < 2; ++nt) oacc[nt] = (f32x4){0.f, 0.f, 0.f, 0.f};

  const u16* vtb = Vt + (size_t)b * (D_ * N_);
  for (int kk = 0; kk < 5; ++kk) {
    u16x8 pa = *(const u16x8*)&pS[l16][kk * 32 + qd * 8];
    const int rl = n0 - 128 + kk * 32 + qd * 8; /* may be <0: P=0 guards */
#pragma unroll
    for (int nt = 0; nt < 2; ++nt) {
      int d = w * 32 + nt * 16 + l16;
      u16x8 vv = *(const u16x8*)(vtb + (size_t)d * N_ + rl);
      oacc[nt] = mfma_f16(pa, vv, oacc[nt]);
    }
  }
#pragma unroll
  for (int nt = 0; nt < 2; ++nt)
#pragma unroll
    for (int r = 0; r < 4; ++r)
      Out[(size_t)(m0 + qd * 4 + r) * D_ + w * 32 + nt * 16 + l16] = oacc[nt][r];
}

extern "C" void kernel_launch(void* const* d_in, const int* in_sizes, int n_in,
                              void* d_out, int out_size, void* d_ws, size_t ws_size,
                              hipStream_t stream) {
  const float* x = (const float*)d_in[0];
  const float* wl = (const float*)d_in[1];
  float* out = (float*)d_out;

  u16* Qf = (u16*)d_ws;
  u16* Kf = Qf + QK_ELEMS;
  u16* Vt = Kf + QK_ELEMS;

  dim3 g1(MTOT / TM, E3 / TE); /* 32 x 24 = 768 blocks = 3/CU exact */
  qkv_gemm<<<g1, 256, 0, stream>>>(x, wl, Qf, Kf, Vt);
  attn_kernel<<<MTOT / TQA, 1024, 0, stream>>>(Qf, Kf, Vt, out);
}